// Round 5
// baseline (218.105 us; speedup 1.0000x reference)
//
#include <hip/hip_runtime.h>

#define NCB 32
#define KK 16
#define DD 128
#define IN_F 4096
#define OUT_F 2048
#define NTOK 2048
#define LUT_BLOCKS (NCB * (OUT_F / 128))  // 512
#define IDX_BLOCKS ((NTOK / 64) * NCB)    // 1024

// ---- Launch A: grid-partitioned fusion of lut-build and idx-argmin (independent) ----
__global__ __launch_bounds__(256, 4) void fused_lut_idx(
    const float* __restrict__ centroids, const float* __restrict__ weight,
    const float* __restrict__ x, float* __restrict__ lut,
    unsigned char* __restrict__ idxb) {
    __shared__ float smem[KK * 164];  // 10.25 KB, covers both branches
    const int tid = threadIdx.x;

    if (blockIdx.x < LUT_BLOCKS) {
        // lut[c][k][o] = sum_d cent[c][k][d] * W[c][d][o]
        // block = (c, o-tile 128); thread = (og: 2 o's, kg: 4 k's)
        const int c = blockIdx.x >> 4;
        const int o0 = (blockIdx.x & 15) * 128;
        const int og = tid & 63;
        const int kg = tid >> 6;
        {
            const float4* cb = (const float4*)(centroids + (size_t)c * KK * DD);
            for (int p = tid; p < KK * DD / 4; p += 256) ((float4*)smem)[p] = cb[p];
        }
        __syncthreads();

        float2 acc[4];
#pragma unroll
        for (int kk = 0; kk < 4; ++kk) acc[kk] = make_float2(0.f, 0.f);
        const float* wb = weight + (size_t)c * DD * OUT_F + o0 + og * 2;
#pragma unroll 4
        for (int dw = 0; dw < DD / 4; ++dw) {
            float2 w0 = *(const float2*)(wb + (size_t)(dw * 4 + 0) * OUT_F);
            float2 w1 = *(const float2*)(wb + (size_t)(dw * 4 + 1) * OUT_F);
            float2 w2 = *(const float2*)(wb + (size_t)(dw * 4 + 2) * OUT_F);
            float2 w3 = *(const float2*)(wb + (size_t)(dw * 4 + 3) * OUT_F);
#pragma unroll
            for (int kk = 0; kk < 4; ++kk) {
                // wave-uniform address -> LDS broadcast, no conflicts
                float4 cv = *(const float4*)(smem + (kg * 4 + kk) * DD + dw * 4);
                acc[kk].x += cv.x * w0.x + cv.y * w1.x + cv.z * w2.x + cv.w * w3.x;
                acc[kk].y += cv.x * w0.y + cv.y * w1.y + cv.z * w2.y + cv.w * w3.y;
            }
        }
#pragma unroll
        for (int kk = 0; kk < 4; ++kk)
            *(float2*)(lut + ((size_t)c * KK + kg * 4 + kk) * OUT_F + o0 + og * 2) = acc[kk];
    } else {
        // idx[t][c] = argmin_k (|cent[c][k]|^2 - 2 x[t].cent[c][k])
        const int bid = blockIdx.x - LUT_BLOCKS;
        const int c = bid & (NCB - 1);
        const int t0 = (bid >> 5) * 64;
        const int th_q = tid & 3;
        const int th_k = (tid >> 2) & 3;
        const int th_t = tid >> 4;

        // bank-engineered centroid layout: q-stride 40, k-stride 164 (max 2-way = free)
        for (int p = tid; p < KK * 32; p += 256) {
            int k = p >> 5, f4 = p & 31;
            int q = f4 >> 3, jj = f4 & 7;
            *(float4*)(smem + k * 164 + q * 40 + jj * 4) =
                *(const float4*)(centroids + ((size_t)c * KK + k) * DD + f4 * 4);
        }
        __syncthreads();

        float acc[4][4], sq[4];
#pragma unroll
        for (int r = 0; r < 4; ++r)
#pragma unroll
            for (int kk = 0; kk < 4; ++kk) acc[r][kk] = 0.f;
#pragma unroll
        for (int kk = 0; kk < 4; ++kk) sq[kk] = 0.f;

        const float* xb0 = x + (size_t)(t0 + th_t * 4) * IN_F + c * DD + th_q * 32;
#pragma unroll
        for (int chunk = 0; chunk < 8; ++chunk) {
            float4 ca[4];
#pragma unroll
            for (int kk = 0; kk < 4; ++kk)
                ca[kk] = *(const float4*)(smem + (th_k * 4 + kk) * 164 + th_q * 40 + chunk * 4);
#pragma unroll
            for (int kk = 0; kk < 4; ++kk)
                sq[kk] += ca[kk].x * ca[kk].x + ca[kk].y * ca[kk].y
                        + ca[kk].z * ca[kk].z + ca[kk].w * ca[kk].w;
#pragma unroll
            for (int r = 0; r < 4; ++r) {
                float4 xr = *(const float4*)(xb0 + (size_t)r * IN_F + chunk * 4);
#pragma unroll
                for (int kk = 0; kk < 4; ++kk)
                    acc[r][kk] += xr.x * ca[kk].x + xr.y * ca[kk].y
                                + xr.z * ca[kk].z + xr.w * ca[kk].w;
            }
        }
#pragma unroll
        for (int kk = 0; kk < 4; ++kk) {
            float a = sq[kk];
            a += __shfl_xor(a, 1);
            a += __shfl_xor(a, 2);
            sq[kk] = a;
        }
#pragma unroll
        for (int r = 0; r < 4; ++r)
#pragma unroll
            for (int kk = 0; kk < 4; ++kk) {
                float a = acc[r][kk];
                a += __shfl_xor(a, 1);
                a += __shfl_xor(a, 2);
                acc[r][kk] = a;
            }
#pragma unroll
        for (int r = 0; r < 4; ++r) {
            float best = sq[0] - 2.f * acc[r][0];
            int bi = th_k * 4;
#pragma unroll
            for (int kk = 1; kk < 4; ++kk) {
                float v = sq[kk] - 2.f * acc[r][kk];
                if (v < best) { best = v; bi = th_k * 4 + kk; }
            }
#pragma unroll
            for (int s = 4; s <= 8; s <<= 1) {
                float ov = __shfl_xor(best, s);
                int oi = __shfl_xor(bi, s);
                if (ov < best || (ov == best && oi < bi)) { best = ov; bi = oi; }
            }
            if ((tid & 15) == 0)
                idxb[(size_t)(t0 + th_t * 4 + r) * NCB + c] = (unsigned char)bi;
        }
    }
}

// ---- Launch B: out[t][o] = bias[o] + sum_c lut[c][idx[t][c]][o] ----
// grid (NTOK/256, OUT_F/32) = 512 blocks = 2/CU (80 KB LDS). Rows padded to 36 floats.
// float4 (b128) inner reads: half the LDS instruction count of the float2 version.
__global__ __launch_bounds__(256) void gather_kernel(const float* __restrict__ lut,
                                                     const unsigned char* __restrict__ idxb,
                                                     const float* __restrict__ bias,
                                                     float* __restrict__ out) {
    const int t0 = blockIdx.x * 256;
    const int o0 = blockIdx.y * 32;
    __shared__ float slut[NCB * KK * 36];      // 72 KB
    __shared__ unsigned char sidx[256 * NCB];  // 8 KB

    {
        const int row = threadIdx.x >> 3;
        const int q = threadIdx.x & 7;
        for (int r = row; r < NCB * KK; r += 32)
            *(float4*)(slut + r * 36 + q * 4) =
                *(const float4*)(lut + (size_t)r * OUT_F + o0 + q * 4);
    }
    {
        const int4* ig = (const int4*)(idxb + (size_t)t0 * NCB);
        int4* is4 = (int4*)sidx;
        for (int i = threadIdx.x; i < 512; i += 256) is4[i] = ig[i];
    }
    __syncthreads();

    const int oo = (threadIdx.x & 7) * 4;
    const int tl = threadIdx.x >> 3;  // 0..31
    const float4 bv = *(const float4*)(bias + o0 + oo);

    for (int tt = tl; tt < 256; tt += 32) {
        float4 acc = bv;
        const unsigned int* ip = (const unsigned int*)(sidx + tt * NCB);
#pragma unroll
        for (int c4 = 0; c4 < NCB / 4; ++c4) {
            unsigned int iv4 = ip[c4];  // 4 packed indices
#pragma unroll
            for (int b = 0; b < 4; ++b) {
                int cc = c4 * 4 + b;
                int iv = (iv4 >> (8 * b)) & 0xff;
                const float4 v = *(const float4*)(slut + (cc * KK + iv) * 36 + oo);
                acc.x += v.x; acc.y += v.y; acc.z += v.z; acc.w += v.w;
            }
        }
        *(float4*)(out + (size_t)(t0 + tt) * OUT_F + o0 + oo) = acc;
    }
}

extern "C" void kernel_launch(void* const* d_in, const int* in_sizes, int n_in,
                              void* d_out, int out_size, void* d_ws, size_t ws_size,
                              hipStream_t stream) {
    const float* x         = (const float*)d_in[0];  // [2,1024,4096]
    const float* centroids = (const float*)d_in[1];  // [32,16,128]
    const float* weight    = (const float*)d_in[2];  // [32,128,2048]
    const float* bias      = (const float*)d_in[4];  // [2048]
    float* out = (float*)d_out;                      // [2048,2048] fp32

    float* lut = (float*)d_ws;                                // 4 MB
    unsigned char* idxb = (unsigned char*)d_ws + (4u << 20);  // 64 KB

    fused_lut_idx<<<LUT_BLOCKS + IDX_BLOCKS, 256, 0, stream>>>(
        centroids, weight, x, lut, idxb);
    gather_kernel<<<dim3(NTOK / 256, OUT_F / 32), 256, 0, stream>>>(lut, idxb, bias, out);
}

// Round 6
// 148.099 us; speedup vs baseline: 1.4727x; 1.4727x over previous
//
#include <hip/hip_runtime.h>

#define NCB 32
#define KK 16
#define DD 128
#define IN_F 4096
#define OUT_F 2048
#define NTOK 2048
#define LUT_BLOCKS 256                 // 32 c x 8 o-tiles(256)
#define IDX_BLOCKS ((NTOK / 64) * NCB) // 1024

// LDS layout for idx branch (floats): xs[64][148] then cs[16][164]
#define XS_STRIDE 148
#define CS_OFF (64 * XS_STRIDE)
#define SMEM_FLOATS (CS_OFF + KK * 164)  // 12096 floats = 47.25 KB

// ---- Launch A: grid-partitioned fusion of lut-build and idx-argmin ----
__global__ __launch_bounds__(256, 4) void fused_lut_idx(
    const float* __restrict__ centroids, const float* __restrict__ weight,
    const float* __restrict__ x, float* __restrict__ lut,
    unsigned char* __restrict__ idxb) {
    __shared__ float smem[SMEM_FLOATS];
    const int tid = threadIdx.x;

    if (blockIdx.x < LUT_BLOCKS) {
        // lut[c][k][o] = sum_d cent[c][k][d] * W[c][d][o]
        // 1 o per thread, all 16 k. Weight read exactly once, coalesced 1KB/wave.
        // cent addresses are wave-uniform -> scalar-pipe loads (no VMEM cost).
        const int c = blockIdx.x >> 3;
        const int o = ((blockIdx.x & 7) << 8) | tid;
        const float* cb = centroids + (size_t)c * KK * DD;
        const float* wb = weight + (size_t)c * DD * OUT_F + o;
        float acc[KK];
#pragma unroll
        for (int k = 0; k < KK; ++k) acc[k] = 0.f;
        for (int d4 = 0; d4 < DD / 4; ++d4) {
            float w0 = wb[(size_t)(d4 * 4 + 0) * OUT_F];
            float w1 = wb[(size_t)(d4 * 4 + 1) * OUT_F];
            float w2 = wb[(size_t)(d4 * 4 + 2) * OUT_F];
            float w3 = wb[(size_t)(d4 * 4 + 3) * OUT_F];
#pragma unroll
            for (int k = 0; k < KK; ++k) {
                float4 cv = *(const float4*)(cb + k * DD + d4 * 4);  // uniform
                acc[k] += cv.x * w0 + cv.y * w1 + cv.z * w2 + cv.w * w3;
            }
        }
#pragma unroll
        for (int k = 0; k < KK; ++k)
            lut[((size_t)c * KK + k) * OUT_F + o] = acc[k];
    } else {
        // idx[t][c] = argmin_k (|cent[c][k]|^2 - 2 x[t].cent[c][k])
        const int bid = blockIdx.x - LUT_BLOCKS;
        const int c = bid & (NCB - 1);
        const int t0 = (bid >> 5) * 64;
        const int th_q = tid & 3;
        const int th_k = (tid >> 2) & 3;
        const int th_t = tid >> 4;
        float* xs = smem;            // [64][148], segment layout q*36+j
        float* cs = smem + CS_OFF;   // [16][164], layout q*40+j

        // stage x tile: 64 tokens x 128 floats (c-slice), coalesced; the ONLY x read.
        {
            const float* xg = x + (size_t)t0 * IN_F + c * DD;
#pragma unroll
            for (int i = 0; i < 8; ++i) {
                int p = i * 256 + tid;           // float4 index
                int t = p >> 5, f4 = p & 31;
                int q = f4 >> 3, jj = f4 & 7;
                float4 v = *(const float4*)(xg + (size_t)t * IN_F + f4 * 4);
                *(float4*)(xs + t * XS_STRIDE + q * 36 + jj * 4) = v;
            }
        }
        // stage centroids (8 KB)
        for (int p = tid; p < KK * 32; p += 256) {
            int k = p >> 5, f4 = p & 31;
            int q = f4 >> 3, jj = f4 & 7;
            *(float4*)(cs + k * 164 + q * 40 + jj * 4) =
                *(const float4*)(centroids + ((size_t)c * KK + k) * DD + f4 * 4);
        }
        __syncthreads();

        float acc[4][4], sq[4];
#pragma unroll
        for (int r = 0; r < 4; ++r)
#pragma unroll
            for (int kk = 0; kk < 4; ++kk) acc[r][kk] = 0.f;
#pragma unroll
        for (int kk = 0; kk < 4; ++kk) sq[kk] = 0.f;

#pragma unroll
        for (int chunk = 0; chunk < 8; ++chunk) {
            float4 ca[4];
#pragma unroll
            for (int kk = 0; kk < 4; ++kk)
                ca[kk] = *(const float4*)(cs + (th_k * 4 + kk) * 164 + th_q * 40 + chunk * 4);
#pragma unroll
            for (int kk = 0; kk < 4; ++kk)
                sq[kk] += ca[kk].x * ca[kk].x + ca[kk].y * ca[kk].y
                        + ca[kk].z * ca[kk].z + ca[kk].w * ca[kk].w;
#pragma unroll
            for (int r = 0; r < 4; ++r) {
                float4 xr = *(const float4*)(xs + (th_t * 4 + r) * XS_STRIDE
                                             + th_q * 36 + chunk * 4);
#pragma unroll
                for (int kk = 0; kk < 4; ++kk)
                    acc[r][kk] += xr.x * ca[kk].x + xr.y * ca[kk].y
                                + xr.z * ca[kk].z + xr.w * ca[kk].w;
            }
        }
#pragma unroll
        for (int kk = 0; kk < 4; ++kk) {
            float a = sq[kk];
            a += __shfl_xor(a, 1);
            a += __shfl_xor(a, 2);
            sq[kk] = a;
        }
#pragma unroll
        for (int r = 0; r < 4; ++r)
#pragma unroll
            for (int kk = 0; kk < 4; ++kk) {
                float a = acc[r][kk];
                a += __shfl_xor(a, 1);
                a += __shfl_xor(a, 2);
                acc[r][kk] = a;
            }
#pragma unroll
        for (int r = 0; r < 4; ++r) {
            float best = sq[0] - 2.f * acc[r][0];
            int bi = th_k * 4;
#pragma unroll
            for (int kk = 1; kk < 4; ++kk) {
                float v = sq[kk] - 2.f * acc[r][kk];
                if (v < best) { best = v; bi = th_k * 4 + kk; }
            }
#pragma unroll
            for (int s = 4; s <= 8; s <<= 1) {
                float ov = __shfl_xor(best, s);
                int oi = __shfl_xor(bi, s);
                if (ov < best || (ov == best && oi < bi)) { best = ov; bi = oi; }
            }
            if ((tid & 15) == 0)
                idxb[(size_t)(t0 + th_t * 4 + r) * NCB + c] = (unsigned char)bi;
        }
    }
}

// ---- Launch B: out[t][o] = bias[o] + sum_c lut[c][idx[t][c]][o] ----
// grid (NTOK/256, OUT_F/32) = 512 blocks = 2/CU (80 KB LDS). Rows padded to 36 floats.
__global__ __launch_bounds__(256) void gather_kernel(const float* __restrict__ lut,
                                                     const unsigned char* __restrict__ idxb,
                                                     const float* __restrict__ bias,
                                                     float* __restrict__ out) {
    const int t0 = blockIdx.x * 256;
    const int o0 = blockIdx.y * 32;
    __shared__ float slut[NCB * KK * 36];      // 72 KB
    __shared__ unsigned char sidx[256 * NCB];  // 8 KB

    {
        const int row = threadIdx.x >> 3;
        const int q = threadIdx.x & 7;
        for (int r = row; r < NCB * KK; r += 32)
            *(float4*)(slut + r * 36 + q * 4) =
                *(const float4*)(lut + (size_t)r * OUT_F + o0 + q * 4);
    }
    {
        const int4* ig = (const int4*)(idxb + (size_t)t0 * NCB);
        int4* is4 = (int4*)sidx;
        for (int i = threadIdx.x; i < 512; i += 256) is4[i] = ig[i];
    }
    __syncthreads();

    const int oo = (threadIdx.x & 7) * 4;
    const int tl = threadIdx.x >> 3;  // 0..31
    const float4 bv = *(const float4*)(bias + o0 + oo);

    for (int tt = tl; tt < 256; tt += 32) {
        float4 acc = bv;
        const unsigned int* ip = (const unsigned int*)(sidx + tt * NCB);
#pragma unroll
        for (int c4 = 0; c4 < NCB / 4; ++c4) {
            unsigned int iv4 = ip[c4];
#pragma unroll
            for (int b = 0; b < 4; ++b) {
                int cc = c4 * 4 + b;
                int iv = (iv4 >> (8 * b)) & 0xff;
                const float4 v = *(const float4*)(slut + (cc * KK + iv) * 36 + oo);
                acc.x += v.x; acc.y += v.y; acc.z += v.z; acc.w += v.w;
            }
        }
        *(float4*)(out + (size_t)(t0 + tt) * OUT_F + o0 + oo) = acc;
    }
}

extern "C" void kernel_launch(void* const* d_in, const int* in_sizes, int n_in,
                              void* d_out, int out_size, void* d_ws, size_t ws_size,
                              hipStream_t stream) {
    const float* x         = (const float*)d_in[0];  // [2,1024,4096]
    const float* centroids = (const float*)d_in[1];  // [32,16,128]
    const float* weight    = (const float*)d_in[2];  // [32,128,2048]
    const float* bias      = (const float*)d_in[4];  // [2048]
    float* out = (float*)d_out;                      // [2048,2048] fp32

    float* lut = (float*)d_ws;                                // 4 MB
    unsigned char* idxb = (unsigned char*)d_ws + (4u << 20);  // 64 KB

    fused_lut_idx<<<LUT_BLOCKS + IDX_BLOCKS, 256, 0, stream>>>(
        centroids, weight, x, lut, idxb);
    gather_kernel<<<dim3(NTOK / 256, OUT_F / 32), 256, 0, stream>>>(lut, idxb, bias, out);
}